// Round 2
// baseline (275.283 us; speedup 1.0000x reference)
//
#include <hip/hip_runtime.h>

// Problem constants
#define BATCH 4096
#define INF   2048
#define OUTF  2048

typedef __attribute__((ext_vector_type(8))) short bf16x8;
typedef __attribute__((ext_vector_type(4))) float f32x4;

// float -> bf16 bits, round-to-nearest-even
__device__ inline unsigned short f2bf(float f) {
  unsigned int u = __float_as_uint(f);
  u += 0x7fffu + ((u >> 16) & 1u);
  return (unsigned short)(u >> 16);
}

// 16B async global->LDS. LDS dest is wave-uniform base; HW writes base + lane*16.
__device__ inline void gld16(const void* g, void* l) {
  __builtin_amdgcn_global_load_lds(
      (const __attribute__((address_space(1))) void*)g,
      (__attribute__((address_space(3))) void*)l,
      16, 0, 0);
}

// Fused pack: x_re,x_im (4096x2048) and w_re,w_im (2048x2048) fp32 -> bf16,
// plain row-major.
__global__ __launch_bounds__(256) void pack_all(const float* __restrict__ xr,
                                                const float* __restrict__ xi,
                                                const float* __restrict__ wr,
                                                const float* __restrict__ wi,
                                                unsigned short* __restrict__ Xre,
                                                unsigned short* __restrict__ Xim,
                                                unsigned short* __restrict__ Wr,
                                                unsigned short* __restrict__ Wi) {
  const int XCH = (BATCH * INF) / 8;   // 1048576 ushort8 chunks for each x matrix
  int t = blockIdx.x * 256 + threadIdx.x;
  const float4 *s0, *s1;
  bf16x8 *d0, *d1;
  int idx;
  if (t < XCH) {
    idx = t;
    s0 = (const float4*)xr; s1 = (const float4*)xi;
    d0 = (bf16x8*)Xre;      d1 = (bf16x8*)Xim;
  } else {
    idx = t - XCH;                      // < (OUTF*INF)/8 = 524288
    s0 = (const float4*)wr; s1 = (const float4*)wi;
    d0 = (bf16x8*)Wr;       d1 = (bf16x8*)Wi;
  }
  float4 a0 = s0[2 * idx], a1 = s0[2 * idx + 1];
  float4 b0 = s1[2 * idx], b1 = s1[2 * idx + 1];
  bf16x8 v0, v1;
  v0[0] = (short)f2bf(a0.x); v0[1] = (short)f2bf(a0.y);
  v0[2] = (short)f2bf(a0.z); v0[3] = (short)f2bf(a0.w);
  v0[4] = (short)f2bf(a1.x); v0[5] = (short)f2bf(a1.y);
  v0[6] = (short)f2bf(a1.z); v0[7] = (short)f2bf(a1.w);
  v1[0] = (short)f2bf(b0.x); v1[1] = (short)f2bf(b0.y);
  v1[2] = (short)f2bf(b0.z); v1[3] = (short)f2bf(b0.w);
  v1[4] = (short)f2bf(b1.x); v1[5] = (short)f2bf(b1.y);
  v1[6] = (short)f2bf(b1.z); v1[7] = (short)f2bf(b1.w);
  d0[idx] = v0;
  d1[idx] = v1;
}

// Fused complex GEMM, 8-phase-style schedule (m194-m201 template ported):
//   block tile 256(M=batch) x 128(N=outf), K-step 32, 512 threads = 8 waves
//   (4M x 2N), per-wave 64x64 output via 4x4 mfma_16x16x32_bf16, 2 accs
//   (re,im) = 128 acc VGPR/lane.
// LDS: 3-buffer ring (depth-2 prefetch), 144 KB total:
//   X (re,im): 3 x 256x32 shorts = 48 KB each; W (r,i): 3 x 128x32 = 24 KB each.
// Per K-step: vmcnt(6)+barrier (drains exactly stage s; stage s+1 stays in
// flight), then 4 phases: {ds_read frags | issue stage(s+2) loads | barrier |
// lgkmcnt(0) | setprio(1) 16 MFMA setprio(0) | barrier}.
// Hazard argument: stage(s+2) writes buf[(s+2)%3], last read at step s-1; every
// wave's step-(s-1) ds_reads are drained by that step's lgkmcnt(0) before it
// passes the step-s top barrier, and stage(s+2) is issued after that barrier.
// LDS chunk swizzle (both sides): c_lds = c ^ s(row), s(row)=(row&3)^((row>>2)&3).
__global__ __launch_bounds__(512, 2) void cgemm(const unsigned short* __restrict__ Xre,
                                                const unsigned short* __restrict__ Xim,
                                                const unsigned short* __restrict__ Wr,
                                                const unsigned short* __restrict__ Wi,
                                                float* __restrict__ out) {
  __shared__ unsigned short sXre[3 * 8192];   // 48 KB  (buffer: 256 rows x 32)
  __shared__ unsigned short sXim[3 * 8192];   // 48 KB
  __shared__ unsigned short sWr [3 * 4096];   // 24 KB  (buffer: 128 rows x 32)
  __shared__ unsigned short sWi [3 * 4096];   // 24 KB

  const int tid  = threadIdx.x;
  const int wid  = tid >> 6;    // 0..7
  const int lane = tid & 63;
  const int lrow = lane & 15;
  const int lhi  = lane >> 4;
  const int wm   = wid >> 1;    // 0..3  (M quadrant)
  const int wn   = wid & 1;     // 0..1  (N half)

  // XCD-aware bijective remap (256 blocks, 8 XCDs): each XCD's 32 blocks share
  // 2 X panels (by in {2x,2x+1}) across all 16 W col-tiles.
  const int wg  = blockIdx.y * 16 + blockIdx.x;
  const int swz = (wg & 7) * 32 + (wg >> 3);
  const int bn0 = (swz & 15) * 128;   // out-feature tile
  const int bm0 = (swz >> 4) * 256;   // batch tile

  // Staging map: thread t covers chunk t (16B) of a 128-row round;
  // row = t>>2, col chunk (t&3)^s(row). X = 2 rounds (256 rows), W = 1 round.
  const int srow = tid >> 2;                        // 0..127
  const int sc   = tid & 3;
  const int ss   = (srow & 3) ^ ((srow >> 2) & 3);  // invariant under row+128
  const int scol = (sc ^ ss) * 8;                   // shorts within 32-wide step

  const unsigned short* gXre = Xre + (size_t)(bm0 + srow) * INF + scol;
  const unsigned short* gXim = Xim + (size_t)(bm0 + srow) * INF + scol;
  const unsigned short* gWr  = Wr  + (size_t)(bn0 + srow) * INF + scol;
  const unsigned short* gWi  = Wi  + (size_t)(bn0 + srow) * INF + scol;

  const int ldw = wid * 1024;   // wave-uniform byte base within a 128-row round

  // Fragment read swizzle: logical k-chunk lhi -> LDS chunk lhi^s(row);
  // s(row)==slane for row = {wm*64|wn*64}+i*16+lrow.
  const int slane  = (lrow & 3) ^ ((lrow >> 2) & 3);
  const int kchunk = (lhi ^ slane) * 8;             // shorts

  f32x4 accre[4][4], accim[4][4];
  const f32x4 zz = {0.f, 0.f, 0.f, 0.f};
#pragma unroll
  for (int i = 0; i < 4; ++i)
#pragma unroll
    for (int j = 0; j < 4; ++j) { accre[i][j] = zz; accim[i][j] = zz; }

  const bf16x8 SGN = {(short)0x8000, (short)0x8000, (short)0x8000, (short)0x8000,
                      (short)0x8000, (short)0x8000, (short)0x8000, (short)0x8000};

#define XFRAG(ARR, RD, I) (*(const bf16x8*)&ARR[(RD) + ((wm * 64 + (I)*16 + lrow) << 5) + kchunk])
#define WFRAG(ARR, RD, J) (*(const bf16x8*)&ARR[(RD) + ((wn * 64 + (J)*16 + lrow) << 5) + kchunk])

#define CMFMA(PI, J, XR, XI) \
  accre[PI][J] = __builtin_amdgcn_mfma_f32_16x16x32_bf16(XR, wr_[J], accre[PI][J], 0, 0, 0); \
  accim[PI][J] = __builtin_amdgcn_mfma_f32_16x16x32_bf16(XR, wi_[J], accim[PI][J], 0, 0, 0); \
  accre[PI][J] = __builtin_amdgcn_mfma_f32_16x16x32_bf16(XI, wn_[J], accre[PI][J], 0, 0, 0); \
  accim[PI][J] = __builtin_amdgcn_mfma_f32_16x16x32_bf16(XI, wr_[J], accim[PI][J], 0, 0, 0);

#define MFMA16(PI, XR, XI) \
  __builtin_amdgcn_s_barrier(); \
  asm volatile("s_waitcnt lgkmcnt(0)" ::: "memory"); \
  __builtin_amdgcn_s_setprio(1); \
  CMFMA(PI, 0, XR, XI) CMFMA(PI, 1, XR, XI) CMFMA(PI, 2, XR, XI) CMFMA(PI, 3, XR, XI) \
  __builtin_amdgcn_s_setprio(0); \
  __builtin_amdgcn_s_barrier();

  // One K-step: 4 phases of 16 MFMA. RDX/RDW = read-buffer short offsets;
  // PRE literal 0/1; WXB/WWB = write-buffer byte offsets; GO = k short offset
  // of stage s+2. Stage issue order (vmcnt FIFO): Xre x2, Xim x2, Wr, Wi.
#define STEP(RDX, RDW, PRE, WXB, WWB, GO)                                              \
  {                                                                                    \
    /* ---- phase 0: W frags + x0, stage Xre ---- */                                   \
    bf16x8 wr_[4], wi_[4], wn_[4];                                                     \
    wr_[0] = WFRAG(sWr, RDW, 0); wr_[1] = WFRAG(sWr, RDW, 1);                          \
    wr_[2] = WFRAG(sWr, RDW, 2); wr_[3] = WFRAG(sWr, RDW, 3);                          \
    wi_[0] = WFRAG(sWi, RDW, 0); wi_[1] = WFRAG(sWi, RDW, 1);                          \
    wi_[2] = WFRAG(sWi, RDW, 2); wi_[3] = WFRAG(sWi, RDW, 3);                          \
    bf16x8 x0r = XFRAG(sXre, RDX, 0), x0i = XFRAG(sXim, RDX, 0);                       \
    if (PRE) {                                                                         \
      gld16(gXre + (GO),                    (char*)sXre + (WXB) + ldw);                \
      gld16(gXre + (GO) + (size_t)128 * INF, (char*)sXre + (WXB) + 8192 + ldw);        \
    }                                                                                  \
    wn_[0] = wi_[0] ^ SGN; wn_[1] = wi_[1] ^ SGN;                                      \
    wn_[2] = wi_[2] ^ SGN; wn_[3] = wi_[3] ^ SGN;                                      \
    MFMA16(0, x0r, x0i)                                                                \
    /* ---- phase 1: x1, stage Xim ---- */                                             \
    bf16x8 x1r = XFRAG(sXre, RDX, 1), x1i = XFRAG(sXim, RDX, 1);                       \
    if (PRE) {                                                                         \
      gld16(gXim + (GO),                    (char*)sXim + (WXB) + ldw);                \
      gld16(gXim + (GO) + (size_t)128 * INF, (char*)sXim + (WXB) + 8192 + ldw);        \
    }                                                                                  \
    MFMA16(1, x1r, x1i)                                                                \
    /* ---- phase 2: x2, stage Wr ---- */                                              \
    bf16x8 x2r = XFRAG(sXre, RDX, 2), x2i = XFRAG(sXim, RDX, 2);                       \
    if (PRE) { gld16(gWr + (GO), (char*)sWr + (WWB) + ldw); }                          \
    MFMA16(2, x2r, x2i)                                                                \
    /* ---- phase 3: x3, stage Wi ---- */                                              \
    bf16x8 x3r = XFRAG(sXre, RDX, 3), x3i = XFRAG(sXim, RDX, 3);                       \
    if (PRE) { gld16(gWi + (GO), (char*)sWi + (WWB) + ldw); }                          \
    MFMA16(3, x3r, x3i)                                                                \
  }

#define STAGEALL(S, B)                                                                 \
  {                                                                                    \
    const int _go = (S) * 32;                                                          \
    const int _xb = (B) * 16384, _wb = (B) * 8192;                                     \
    gld16(gXre + _go,                     (char*)sXre + _xb + ldw);                    \
    gld16(gXre + _go + (size_t)128 * INF, (char*)sXre + _xb + 8192 + ldw);             \
    gld16(gXim + _go,                     (char*)sXim + _xb + ldw);                    \
    gld16(gXim + _go + (size_t)128 * INF, (char*)sXim + _xb + 8192 + ldw);             \
    gld16(gWr + _go,                      (char*)sWr + _wb + ldw);                     \
    gld16(gWi + _go,                      (char*)sWi + _wb + ldw);                     \
  }

  // Prologue: fill depth-2 pipeline (12 loads outstanding).
  STAGEALL(0, 0)
  STAGEALL(1, 1)

  // Steady state: 62 steps with prefetch of s+2. Entering each step: 12 loads
  // outstanding; vmcnt(6) drains exactly stage s (FIFO oldest-first).
  int rb = 0, wb = 2;
  for (int s = 0; s < 62; ++s) {
    const int rdx = rb * 8192, rdw = rb * 4096;
    const int wxb = wb * 16384, wwb = wb * 8192;
    const int go  = (s + 2) * 32;
    asm volatile("s_waitcnt vmcnt(6)" ::: "memory");
    __builtin_amdgcn_s_barrier();
    STEP(rdx, rdw, 1, wxb, wwb, go)
    rb = (rb == 2) ? 0 : rb + 1;
    wb = (wb == 2) ? 0 : wb + 1;
  }
  // Step 62 (buffer 2): stages 62,63 outstanding -> vmcnt(6) drains stage 62.
  asm volatile("s_waitcnt vmcnt(6)" ::: "memory");
  __builtin_amdgcn_s_barrier();
  STEP(2 * 8192, 2 * 4096, 0, 0, 0, 0)
  // Step 63 (buffer 0): drain everything.
  asm volatile("s_waitcnt vmcnt(0)" ::: "memory");
  __builtin_amdgcn_s_barrier();
  STEP(0, 0, 0, 0, 0, 0)

#undef STEP
#undef STAGEALL
#undef MFMA16
#undef CMFMA
#undef XFRAG
#undef WFRAG

  // Epilogue: C/D layout col=lane&15, row=(lane>>4)*4+reg. Interleaved {re,im}.
  const int row0 = bm0 + wm * 64 + lhi * 4;
  const int col0 = bn0 + wn * 64 + lrow;
#pragma unroll
  for (int i = 0; i < 4; ++i)
#pragma unroll
    for (int j = 0; j < 4; ++j)
#pragma unroll
      for (int r = 0; r < 4; ++r) {
        int row = row0 + i * 16 + r;
        int col = col0 + j * 16;
        float2 v = make_float2(accre[i][j][r], accim[i][j][r]);
        *(float2*)&out[((size_t)row * OUTF + col) * 2] = v;
      }
}

// Safety fallback if workspace too small: fp32 vector path (slow but correct)
__global__ __launch_bounds__(256) void naive_cx(const float* __restrict__ xr,
                                                const float* __restrict__ xi,
                                                const float* __restrict__ wr,
                                                const float* __restrict__ wi,
                                                float* __restrict__ out) {
  int t = blockIdx.x * 256 + threadIdx.x;
  int b = t >> 11, o = t & 2047;
  const float* xrb = xr + (size_t)b * INF;
  const float* xib = xi + (size_t)b * INF;
  const float* wrb = wr + (size_t)o * INF;
  const float* wib = wi + (size_t)o * INF;
  float are = 0.f, aim = 0.f;
  for (int i = 0; i < INF; ++i) {
    float a = xrb[i], c = xib[i], p = wrb[i], q = wib[i];
    are += a * p - c * q;
    aim += a * q + c * p;
  }
  out[(size_t)t * 2 + 0] = are;
  out[(size_t)t * 2 + 1] = aim;
}

extern "C" void kernel_launch(void* const* d_in, const int* in_sizes, int n_in,
                              void* d_out, int out_size, void* d_ws, size_t ws_size,
                              hipStream_t stream) {
  const float* xr = (const float*)d_in[0];
  const float* xi = (const float*)d_in[1];
  const float* wr = (const float*)d_in[2];
  const float* wi = (const float*)d_in[3];
  float* out = (float*)d_out;

  const size_t nx = (size_t)BATCH * INF;   // 8M elements per x matrix
  const size_t nw = (size_t)OUTF * INF;    // 4M elements per w matrix
  const size_t need = (2 * nx + 2 * nw) * sizeof(unsigned short);  // 48 MiB

  if (ws_size < need) {
    naive_cx<<<(BATCH * OUTF) / 256, 256, 0, stream>>>(xr, xi, wr, wi, out);
    return;
  }

  unsigned short* Xre = (unsigned short*)d_ws;
  unsigned short* Xim = Xre + nx;
  unsigned short* Wr  = Xim + nx;
  unsigned short* Wi  = Wr + nw;

  // pack_all: one thread per ushort8 chunk of each (re,im) pair
  const int grid_pack = (int)((nx / 8 + nw / 8) / 256);           // 6144
  pack_all<<<grid_pack, 256, 0, stream>>>(xr, xi, wr, wi, Xre, Xim, Wr, Wi);

  // 256 blocks = 1 per CU; in-kernel XCD-aware remap.
  dim3 grid(OUTF / 128, BATCH / 256);   // (16, 16)
  cgemm<<<grid, 512, 0, stream>>>(Xre, Xim, Wr, Wi, out);
}